// Round 1
// 524.193 us; speedup vs baseline: 1.0773x; 1.0773x over previous
//
#include <hip/hip_runtime.h>

#define T_N 1024
#define B_N 64
#define A_N 128
#define TP1 1025
// STOP_IX=0, CONT_IX=1, ABSTRACT_PENALTY=0.5, CONSISTENCY_RATIO=1.0

typedef float f32x4 __attribute__((ext_vector_type(4)));

__device__ __forceinline__ float bcf(int x){ return __builtin_bit_cast(float, x); }
__device__ __forceinline__ int   bci(float x){ return __builtin_bit_cast(int, x); }

// ---- DPP helpers ----
template<int CTRL, int RM>
__device__ __forceinline__ float dpp_add_step(float x){
  int t = __builtin_amdgcn_update_dpp(0, bci(x), CTRL, RM, 0xf, true);
  return x + bcf(t);
}
__device__ __forceinline__ float wave_sum64(float x){
  x = dpp_add_step<0x111,0xf>(x);   // row_shr:1
  x = dpp_add_step<0x112,0xf>(x);   // row_shr:2
  x = dpp_add_step<0x114,0xf>(x);   // row_shr:4
  x = dpp_add_step<0x118,0xf>(x);   // row_shr:8
  x = dpp_add_step<0x142,0xa>(x);   // row_bcast15
  x = dpp_add_step<0x143,0xc>(x);   // row_bcast31; lane63 = total
  return bcf(__builtin_amdgcn_readlane(bci(x), 63));
}
// two interleaved reductions: ~1 chain latency for 2 sums
__device__ __forceinline__ void wave_sum64_x2(float a, float b, float& ra, float& rb){
  a = dpp_add_step<0x111,0xf>(a);  b = dpp_add_step<0x111,0xf>(b);
  a = dpp_add_step<0x112,0xf>(a);  b = dpp_add_step<0x112,0xf>(b);
  a = dpp_add_step<0x114,0xf>(a);  b = dpp_add_step<0x114,0xf>(b);
  a = dpp_add_step<0x118,0xf>(a);  b = dpp_add_step<0x118,0xf>(b);
  a = dpp_add_step<0x142,0xa>(a);  b = dpp_add_step<0x142,0xa>(b);
  a = dpp_add_step<0x143,0xc>(a);  b = dpp_add_step<0x143,0xc>(b);
  ra = bcf(__builtin_amdgcn_readlane(bci(a), 63));
  rb = bcf(__builtin_amdgcn_readlane(bci(b), 63));
}
__device__ __forceinline__ float group16_sum(float x){
  x = dpp_add_step<0x111,0xf>(x);
  x = dpp_add_step<0x112,0xf>(x);
  x = dpp_add_step<0x114,0xf>(x);
  x = dpp_add_step<0x118,0xf>(x);
  return x;                          // lane 15 of each 16-group has group sum
}
template<int CTRL, int RM>
__device__ __forceinline__ float dpp_max_step(float x){
  int t = __builtin_amdgcn_update_dpp(bci(-3.4e38f), bci(x), CTRL, RM, 0xf, false);
  return fmaxf(x, bcf(t));
}
__device__ __forceinline__ float wave_max64(float x){
  x = dpp_max_step<0x111,0xf>(x);
  x = dpp_max_step<0x112,0xf>(x);
  x = dpp_max_step<0x114,0xf>(x);
  x = dpp_max_step<0x118,0xf>(x);
  x = dpp_max_step<0x142,0xa>(x);
  x = dpp_max_step<0x143,0xc>(x);
  return bcf(__builtin_amdgcn_readlane(bci(x), 63));
}

// =============== K0: fully-parallel prep ===============
// Per pair p (steps i1=2p+1, i2=2p+2), precompute the 7 coefficient vectors and
// the scalar kappa so the serial scan's loop body is loads + 2 dots + 3 fma.
//   A  = esw1              (dot1 weights -> r_{i1})
//   Q  = ecw1*esw2         (dot2 weights -> r_{i2} partial)
//   CC = ecw1*ecw2         (z jump)
//   SC = sv1*ecw2          (z jump, r1 term)
//   SV1= sv1, SV2 = sv2    (interior store / z jump)
//   E1 = ecw1              (interior store)
//   kap= sum_b sv1*esw2    (scalar: r2 = dot2 + kap*r1)
// Also zeros A1p and computes cont chunk sums cs[16][64] (input-only work
// pulled out of the single-block post kernel).
__global__ __launch_bounds__(256) void prep_kernel(
    const float* __restrict__ stop_logps,
    const float* __restrict__ start_logps,
    float* __restrict__ pairA,   // [512][7][64]
    float* __restrict__ kap,     // [512]
    float* __restrict__ cs,      // [16][64]
    float* __restrict__ A1p)     // 64*1024, zeroed here
{
  const int tid  = (int)threadIdx.x;
  const int lane = tid & 63;
  const int wv   = tid >> 6;
  const int p    = (int)blockIdx.x * 4 + wv;   // 0..511
  const float KAPPA = 0.60653065971263342f;    // e^-0.5
  const float2* stop2 = (const float2*)stop_logps;

  // zero A1p: 65536 floats / 32768 threads = 2 each
  int g = (int)blockIdx.x * 256 + tid;
  A1p[g] = 0.f;
  A1p[g + 32768] = 0.f;

  if (p < 511) {
    const int i1 = 2 * p + 1, i2 = 2 * p + 2;
    float2 s1 = stop2[i1 * B_N + lane];
    float2 s2 = stop2[i2 * B_N + lane];
    float st1 = start_logps[i1 * B_N + lane];
    float st2 = start_logps[i2 * B_N + lane];
    float esw1 = __expf(s1.x), ecw1 = __expf(s1.y), sv1 = KAPPA * __expf(st1);
    float esw2 = __expf(s2.x), ecw2 = __expf(s2.y), sv2 = KAPPA * __expf(st2);
    float* pb = pairA + (size_t)p * 7 * B_N;
    pb[0 * B_N + lane] = esw1;
    pb[1 * B_N + lane] = ecw1 * esw2;
    pb[2 * B_N + lane] = ecw1 * ecw2;
    pb[3 * B_N + lane] = sv1 * ecw2;
    pb[4 * B_N + lane] = sv1;
    pb[5 * B_N + lane] = sv2;
    pb[6 * B_N + lane] = ecw1;
    float kp = wave_sum64(sv1 * esw2);
    if (lane == 0) kap[p] = kp;
  }

  // cont chunk sums (chunk c = i in [64c+1, 64c+64])
  if (blockIdx.x < 16 && wv == 0) {
    int c = (int)blockIdx.x;
    float s = 0.f;
    for (int k = 1; k <= 64; ++k) {
      int i = 64 * c + k;
      if (i <= 1023) s += stop2[i * B_N + lane].y;
    }
    cs[c * B_N + lane] = s;
  }
}

// =============== K1: serial scan, paired steps ===============
// Linear recurrence z' = c.z + r*s, r = e.z. Two steps fused:
//   d1 = sum(z*A); d2 = sum(z*Q)   (concurrent DPP chains)
//   r1 = d1; r2 = fma(kap, d1, d2)
//   z_i1 = fma(d1, SV1, z*E1)  (store)
//   z    = fma(z, CC, fma(r2, SV2, d1*SC))  (store)
// Window-of-16 rescale identical to the sequential version: after pair q==7
// (step i = 16m+16), pull r2's exponent, ldexp z, record wexp[m].
__global__ __launch_bounds__(64, 1) void scan_kernel(
    const float* __restrict__ stop_logps,
    const float* __restrict__ start_logps,
    const float* __restrict__ pairA,
    const float* __restrict__ kap,
    float* __restrict__ z_ws,     // (1024,64) rows 1..1023
    float* __restrict__ r_ws,     // 1024
    float* __restrict__ wexp)     // 64 (0..62 used)
{
  const int lane = threadIdx.x;
  float z = __expf(start_logps[lane]);   // y_0, scale P=0

  // 8-pair (16-step) rotating prefetch
  float pb[8][7];
  float kp[8];
  #pragma unroll
  for (int q = 0; q < 8; ++q) {
    #pragma unroll
    for (int v = 0; v < 7; ++v) pb[q][v] = pairA[(q * 7 + v) * B_N + lane];
    kp[q] = kap[q];
  }

  for (int P0 = 0; P0 < 504; P0 += 8) {
    #pragma unroll
    for (int q = 0; q < 8; ++q) {
      const int p  = P0 + q;
      const int i1 = 2 * p + 1;
      float A  = pb[q][0], Q  = pb[q][1], CC = pb[q][2], SC = pb[q][3];
      float SV1= pb[q][4], SV2= pb[q][5], E1 = pb[q][6];
      float kpp = kp[q];
      // prefetch pair p+8 (pairA has a 512th dummy slot; value never used)
      #pragma unroll
      for (int v = 0; v < 7; ++v) pb[q][v] = pairA[((size_t)(p + 8) * 7 + v) * B_N + lane];
      kp[q] = kap[p + 8 < 512 ? p + 8 : 511];

      float d1, d2;
      wave_sum64_x2(z * A, z * Q, d1, d2);
      float r2 = __builtin_fmaf(kpp, d1, d2);
      float z1 = __builtin_fmaf(d1, SV1, z * E1);
      z_ws[i1 * B_N + lane] = z1;
      r_ws[i1]     = d1;
      r_ws[i1 + 1] = r2;
      z = __builtin_fmaf(z, CC, __builtin_fmaf(r2, SV2, d1 * SC));
      z_ws[(i1 + 1) * B_N + lane] = z;

      if (q == 7) {                       // i1+1 = 16m+16: window boundary
        int rb  = bci(r2);
        int e16 = ((rb >> 23) & 255) - 127;
        z = ldexpf(z, -e16);
        wexp[p >> 3] = (float)e16;
      }
    }
  }
  // pairs 504..510 (steps 1009..1022), window 63, no rescale
  #pragma unroll
  for (int q = 0; q < 7; ++q) {
    const int p  = 504 + q;
    const int i1 = 2 * p + 1;
    float A  = pb[q][0], Q  = pb[q][1], CC = pb[q][2], SC = pb[q][3];
    float SV1= pb[q][4], SV2= pb[q][5], E1 = pb[q][6];
    float kpp = kp[q];
    float d1, d2;
    wave_sum64_x2(z * A, z * Q, d1, d2);
    float r2 = __builtin_fmaf(kpp, d1, d2);
    float z1 = __builtin_fmaf(d1, SV1, z * E1);
    z_ws[i1 * B_N + lane] = z1;
    r_ws[i1]     = d1;
    r_ws[i1 + 1] = r2;
    z = __builtin_fmaf(z, CC, __builtin_fmaf(r2, SV2, d1 * SC));
    z_ws[(i1 + 1) * B_N + lane] = z;
  }
  // final single step i=1023
  {
    const float KAPPA = 0.60653065971263342f;
    const float2* stop2 = (const float2*)stop_logps;
    float2 sc = stop2[1023 * B_N + lane];
    float  st = start_logps[1023 * B_N + lane];
    float esw = __expf(sc.x), ecw = __expf(sc.y), sv = KAPPA * __expf(st);
    float r = wave_sum64(z * esw);
    z = __builtin_fmaf(sv, r, z * ecw);
    z_ws[1023 * B_N + lane] = z;
    r_ws[1023] = r;
  }
}

// =============== K2: bookkeeping (slimmed: chunk sums from K0) ===============
__global__ __launch_bounds__(1024) void post_kernel(
    const int* __restrict__ actions,
    const float* __restrict__ action_logps,
    const float* __restrict__ stop_logps,
    const float* __restrict__ start_logps,
    const float* __restrict__ z_ws,
    const float* __restrict__ r_ws,
    const float* __restrict__ wexp,
    const float* __restrict__ cs,
    float* __restrict__ u_ws,
    float* __restrict__ D_ws,
    float* __restrict__ out)
{
  const int tid  = (int)threadIdx.x;
  const int w    = tid >> 6;     // 0..15
  const int lane = tid & 63;     // = b
  const float LN2 = 0.69314718055994531f;
  const float2* stop2 = (const float2*)stop_logps;

  __shared__ float Pw[64];
  if (w == 0) {   // window-scale prefix: Pw[m] = ln2 * sum_{m'<m} wexp[m']
    float psum = 0.f;
    for (int m = 0; m < lane && m < 63; ++m) psum += wexp[m];
    Pw[lane] = psum * LN2;
  }
  __syncthreads();

  float C = 0.f;
  for (int ww = 0; ww < w; ++ww) C += cs[ww * B_N + lane];
  for (int k = 1; k <= 64; ++k) {
    int i = 64 * w + k;
    if (i > 1023) break;
    C += stop2[i * B_N + lane].y;
    float Pv = Pw[(i - 1) >> 4];
    float R  = __logf(r_ws[i]) + Pv - 0.5f;
    u_ws[i * B_N + lane] = start_logps[i * B_N + lane] + R - C;
    float zs = wave_sum64(z_ws[i * B_N + lane]);
    D_ws[i * B_N + lane] = C - (__logf(zs) + Pv);
  }
  if (tid < 64) u_ws[lane] = start_logps[lane];   // u_0 = st0

  if (w == 15) {
    float st0 = start_logps[lane];
    int   a0  = actions[0];
    float al0 = action_logps[lane * A_N + a0];
    float lp0 = __logf(wave_sum64(__expf(st0 + al0)));
    float stopT = stop_logps[(T_N * B_N + lane) * 2 + 0];
    float z1023 = z_ws[1023 * B_N + lane];
    float fin = __logf(wave_sum64(z1023 * __expf(stopT))) + Pw[63];
    if (lane == 0) out[0] = -(lp0 + fin);
  }
}

// =============== K34: fused consistency + logp ===============
// blocks 0..511   : cons rows j = bid and 1023-bid (constant 1025 rows/block
//                   -> perfect byte balance on the 134 MB stream)
// blocks 512..1534: logp term for i = 1535-bid (1023..1, longest first)
__global__ __launch_bounds__(256) void cons_logp_kernel(
    const float* __restrict__ cons_pen,
    const float* __restrict__ u_ws,
    const float* __restrict__ D_ws,
    const int* __restrict__ actions,
    const float* __restrict__ action_logps,
    float* __restrict__ A1p,
    float* __restrict__ LQ)
{
  const int bid  = (int)blockIdx.x;
  const int tid  = (int)threadIdx.x;
  const int lane = tid & 63;
  const int wv   = tid >> 6;

  __shared__ float sm[4][64];
  __shared__ float sa[4][64];

  if (bid < 512) {
    const int bq  = (lane & 15) * 4;
    const int row = lane >> 4;
    #pragma unroll
    for (int t = 0; t < 2; ++t) {
      const int j = t ? (1023 - bid) : bid;
      const float4 u4 = *(const float4*)(u_ws + j * B_N + bq);
      float* dst = A1p + ((j & 63) << 10);
      for (int i0 = j + 4 * wv; i0 <= 1023; i0 += 16) {
        int i  = i0 + row;
        int iL = i > 1023 ? 1023 : i;
        f32x4 cp4 = __builtin_nontemporal_load(
            (const f32x4*)(cons_pen + ((size_t)j * TP1 + iL) * B_N + bq));
        float4 d4  = *(const float4*)(D_ws + (size_t)iL * B_N + bq);
        bool valid = (i >= 1) && (i <= 1023);
        float a0 = u4.x + d4.x + cp4.x;
        float a1 = u4.y + d4.y + cp4.y;
        float a2 = u4.z + d4.z + cp4.z;
        float a3 = u4.w + d4.w + cp4.w;
        a0 = valid ? a0 : -1e30f;
        a1 = valid ? a1 : -1e30f;
        a2 = valid ? a2 : -1e30f;
        a3 = valid ? a3 : -1e30f;
        float sred = (__expf(a0) + __expf(a1)) + (__expf(a2) + __expf(a3));
        sred = group16_sum(sred);
        if (((lane & 15) == 15) && valid) atomicAdd(dst + i, sred);
      }
    }
  } else {
    const int i = 1535 - bid;   // 1023..1
    int   ai = actions[i];
    float av = action_logps[((size_t)i * B_N + lane) * A_N + ai];

    float m = -1e30f, acc = 0.f;
    for (int jj = wv; jj <= i; jj += 4) {
      float u  = u_ws[jj * B_N + lane];
      float nm = fmaxf(m, u);
      acc = acc * __expf(m - nm) + __expf(u - nm);
      m = nm;
    }
    sm[wv][lane] = m; sa[wv][lane] = acc;
    __syncthreads();
    if (wv == 0) {
      float m0 = sm[0][lane], m1 = sm[1][lane], m2 = sm[2][lane], m3 = sm[3][lane];
      float M2 = fmaxf(fmaxf(m0, m1), fmaxf(m2, m3));
      float A  = sa[0][lane] * __expf(m0 - M2) + sa[1][lane] * __expf(m1 - M2)
               + sa[2][lane] * __expf(m2 - M2) + sa[3][lane] * __expf(m3 - M2);
      float S  = M2 + __logf(A);
      float val = S + D_ws[(size_t)i * B_N + lane] + av;
      float mx  = wave_max64(val);
      float sum = wave_sum64(__expf(val - mx));
      if (lane == 0) LQ[i] = mx + __logf(sum);
    }
  }
}

// =============== K5: combine ===============
__global__ __launch_bounds__(256) void finish_kernel(
    const float* __restrict__ A1p,
    const float* __restrict__ LQ,
    float* __restrict__ out)
{
  const int i = (int)blockIdx.x * 256 + (int)threadIdx.x;   // grid 4
  float v = 0.f;
  if (i >= 1 && i <= 1023) {
    float a = 0.f;
    #pragma unroll 8
    for (int p = 0; p < 64; ++p) a += A1p[(p << 10) + i];
    v = __logf(a) - LQ[i];
  }
  float ws = wave_sum64(v);
  __shared__ float sb[4];
  if ((threadIdx.x & 63) == 0) sb[threadIdx.x >> 6] = ws;
  __syncthreads();
  if (threadIdx.x == 0) atomicAdd(out, sb[0] + sb[1] + sb[2] + sb[3]);
}

extern "C" void kernel_launch(void* const* d_in, const int* in_sizes, int n_in,
                              void* d_out, int out_size, void* d_ws, size_t ws_size,
                              hipStream_t stream) {
  const int*   actions      = (const int*)d_in[0];
  const float* action_logps = (const float*)d_in[1];
  const float* stop_logps   = (const float*)d_in[2];
  const float* start_logps  = (const float*)d_in[3];
  const float* cons_pen     = (const float*)d_in[4];
  float* out = (float*)d_out;

  float* z_ws  = (float*)d_ws;                  // 1024*64
  float* u_ws  = z_ws + T_N * B_N;              // 1024*64
  float* D_ws  = u_ws + T_N * B_N;              // 1024*64
  float* A1p   = D_ws + T_N * B_N;              // 64*1024
  float* r_ws  = A1p + 64 * 1024;               // 1024
  float* wexp  = r_ws + T_N;                    // 64
  float* LQ    = wexp + 64;                     // 1024
  float* cs    = LQ + T_N;                      // 16*64
  float* pairA = cs + 16 * B_N;                 // 512*7*64
  float* kap   = pairA + 512 * 7 * B_N;         // 512   (total ~2.0 MB)

  hipLaunchKernelGGL(prep_kernel, dim3(128), dim3(256), 0, stream,
                     stop_logps, start_logps, pairA, kap, cs, A1p);
  hipLaunchKernelGGL(scan_kernel, dim3(1), dim3(64), 0, stream,
                     stop_logps, start_logps, pairA, kap, z_ws, r_ws, wexp);
  hipLaunchKernelGGL(post_kernel, dim3(1), dim3(1024), 0, stream,
                     actions, action_logps, stop_logps, start_logps,
                     z_ws, r_ws, wexp, cs, u_ws, D_ws, out);
  hipLaunchKernelGGL(cons_logp_kernel, dim3(1535), dim3(256), 0, stream,
                     cons_pen, u_ws, D_ws, actions, action_logps, A1p, LQ);
  hipLaunchKernelGGL(finish_kernel, dim3(4), dim3(256), 0, stream,
                     A1p, LQ, out);
}

// Round 2
// 489.723 us; speedup vs baseline: 1.1531x; 1.0704x over previous
//
#include <hip/hip_runtime.h>

#define T_N 1024
#define B_N 64
#define A_N 128
#define TP1 1025
// STOP_IX=0, CONT_IX=1, ABSTRACT_PENALTY=0.5, CONSISTENCY_RATIO=1.0

typedef float f32x4 __attribute__((ext_vector_type(4)));

__device__ __forceinline__ float bcf(int x){ return __builtin_bit_cast(float, x); }
__device__ __forceinline__ int   bci(float x){ return __builtin_bit_cast(int, x); }

// ---- DPP helpers ----
template<int CTRL, int RM>
__device__ __forceinline__ float dpp_add_step(float x){
  int t = __builtin_amdgcn_update_dpp(0, bci(x), CTRL, RM, 0xf, true);
  return x + bcf(t);
}
__device__ __forceinline__ float wave_sum64(float x){
  x = dpp_add_step<0x111,0xf>(x);   // row_shr:1
  x = dpp_add_step<0x112,0xf>(x);   // row_shr:2
  x = dpp_add_step<0x114,0xf>(x);   // row_shr:4
  x = dpp_add_step<0x118,0xf>(x);   // row_shr:8
  x = dpp_add_step<0x142,0xa>(x);   // row_bcast15
  x = dpp_add_step<0x143,0xc>(x);   // row_bcast31; lane63 = total
  return bcf(__builtin_amdgcn_readlane(bci(x), 63));
}
// four interleaved reductions: ~1 chain latency for 4 sums
__device__ __forceinline__ void wave_sum64_x4(float a, float b, float c, float d,
                                              float& ra, float& rb, float& rc, float& rd){
  a = dpp_add_step<0x111,0xf>(a); b = dpp_add_step<0x111,0xf>(b);
  c = dpp_add_step<0x111,0xf>(c); d = dpp_add_step<0x111,0xf>(d);
  a = dpp_add_step<0x112,0xf>(a); b = dpp_add_step<0x112,0xf>(b);
  c = dpp_add_step<0x112,0xf>(c); d = dpp_add_step<0x112,0xf>(d);
  a = dpp_add_step<0x114,0xf>(a); b = dpp_add_step<0x114,0xf>(b);
  c = dpp_add_step<0x114,0xf>(c); d = dpp_add_step<0x114,0xf>(d);
  a = dpp_add_step<0x118,0xf>(a); b = dpp_add_step<0x118,0xf>(b);
  c = dpp_add_step<0x118,0xf>(c); d = dpp_add_step<0x118,0xf>(d);
  a = dpp_add_step<0x142,0xa>(a); b = dpp_add_step<0x142,0xa>(b);
  c = dpp_add_step<0x142,0xa>(c); d = dpp_add_step<0x142,0xa>(d);
  a = dpp_add_step<0x143,0xc>(a); b = dpp_add_step<0x143,0xc>(b);
  c = dpp_add_step<0x143,0xc>(c); d = dpp_add_step<0x143,0xc>(d);
  ra = bcf(__builtin_amdgcn_readlane(bci(a), 63));
  rb = bcf(__builtin_amdgcn_readlane(bci(b), 63));
  rc = bcf(__builtin_amdgcn_readlane(bci(c), 63));
  rd = bcf(__builtin_amdgcn_readlane(bci(d), 63));
}
__device__ __forceinline__ float group16_sum(float x){
  x = dpp_add_step<0x111,0xf>(x);
  x = dpp_add_step<0x112,0xf>(x);
  x = dpp_add_step<0x114,0xf>(x);
  x = dpp_add_step<0x118,0xf>(x);
  return x;                          // lane 15 of each 16-group has group sum
}
template<int CTRL, int RM>
__device__ __forceinline__ float dpp_max_step(float x){
  int t = __builtin_amdgcn_update_dpp(bci(-3.4e38f), bci(x), CTRL, RM, 0xf, false);
  return fmaxf(x, bcf(t));
}
__device__ __forceinline__ float wave_max64(float x){
  x = dpp_max_step<0x111,0xf>(x);
  x = dpp_max_step<0x112,0xf>(x);
  x = dpp_max_step<0x114,0xf>(x);
  x = dpp_max_step<0x118,0xf>(x);
  x = dpp_max_step<0x142,0xa>(x);
  x = dpp_max_step<0x143,0xc>(x);
  return bcf(__builtin_amdgcn_readlane(bci(x), 63));
}

// =============== K0: fully-parallel prep (quad coefficients) ===============
// Quad p covers steps i = 4p+1 .. 4p+4 (p = 0..254; steps 1021..1023 are
// handled as singles in the scan). Per quad, 5 packed float4 slots per lane:
//   s0 = {V1,V2,V3,V4}   dot vectors: V1=e1, V2=e2c1, V3=e3c2c1, V4=e4c3c2c1
//   s1 = {c1,s1,c2,s2}   z-chain coefficients (s_k = kappa*e^{start_k})
//   s2 = {c3,s3,c4,s4}
//   s3 = {k21,k31,k32,k41}  scalar couplings (uniform across lanes)
//   s4 = {k42,k43,0,0}
// where r1=V1.z0; r2=V2.z0+k21 r1; r3=V3.z0+k31 r1+k32 r2;
//       r4=V4.z0+k41 r1+k42 r2+k43 r3;  z_k = c_k z_{k-1} + r_k s_k.
// Also zeros A1p and computes cont chunk sums cs[16][64].
__global__ __launch_bounds__(256) void prep_kernel(
    const float* __restrict__ stop_logps,
    const float* __restrict__ start_logps,
    float* __restrict__ quadQ,   // [256][5][64][4] (quad 255 = dummy)
    float* __restrict__ cs,      // [16][64]
    float* __restrict__ A1p)     // 64*1024, zeroed here
{
  const int tid  = (int)threadIdx.x;
  const int lane = tid & 63;
  const int wv   = tid >> 6;
  const int p    = (int)blockIdx.x * 4 + wv;   // 0..255
  const float KAPPA = 0.60653065971263342f;    // e^-0.5
  const float2* stop2 = (const float2*)stop_logps;

  // zero A1p: 65536 floats / 16384 threads = 4 each
  int g = (int)blockIdx.x * 256 + tid;
  A1p[g] = 0.f; A1p[g + 16384] = 0.f; A1p[g + 32768] = 0.f; A1p[g + 49152] = 0.f;

  if (p < 255) {
    const int i1 = 4 * p + 1;
    float2 q1 = stop2[(i1 + 0) * B_N + lane];
    float2 q2 = stop2[(i1 + 1) * B_N + lane];
    float2 q3 = stop2[(i1 + 2) * B_N + lane];
    float2 q4 = stop2[(i1 + 3) * B_N + lane];
    float t1 = start_logps[(i1 + 0) * B_N + lane];
    float t2 = start_logps[(i1 + 1) * B_N + lane];
    float t3 = start_logps[(i1 + 2) * B_N + lane];
    float t4 = start_logps[(i1 + 3) * B_N + lane];
    float e1 = __expf(q1.x), c1 = __expf(q1.y), s1 = KAPPA * __expf(t1);
    float e2 = __expf(q2.x), c2 = __expf(q2.y), s2 = KAPPA * __expf(t2);
    float e3 = __expf(q3.x), c3 = __expf(q3.y), s3 = KAPPA * __expf(t3);
    float e4 = __expf(q4.x), c4 = __expf(q4.y), s4 = KAPPA * __expf(t4);

    float V1 = e1;
    float V2 = e2 * c1;
    float V3 = e3 * c2 * c1;
    float V4 = e4 * c3 * c2 * c1;

    float k21 = wave_sum64(e2 * s1);
    float k31 = wave_sum64(e3 * c2 * s1);
    float k32 = wave_sum64(e3 * s2);
    float k41 = wave_sum64(e4 * c3 * c2 * s1);
    float k42 = wave_sum64(e4 * c3 * s2);
    float k43 = wave_sum64(e4 * s3);

    f32x4* qs = (f32x4*)quadQ;
    size_t base = (size_t)p * 5 * 64 + lane;
    qs[base + 0 * 64] = (f32x4){V1, V2, V3, V4};
    qs[base + 1 * 64] = (f32x4){c1, s1, c2, s2};
    qs[base + 2 * 64] = (f32x4){c3, s3, c4, s4};
    qs[base + 3 * 64] = (f32x4){k21, k31, k32, k41};
    qs[base + 4 * 64] = (f32x4){k42, k43, 0.f, 0.f};
  }

  // cont chunk sums (chunk c = i in [64c+1, 64c+64])
  if (blockIdx.x < 16 && wv == 0) {
    int c = (int)blockIdx.x;
    float s = 0.f;
    for (int k = 1; k <= 64; ++k) {
      int i = 64 * c + k;
      if (i <= 1023) s += stop2[i * B_N + lane].y;
    }
    cs[c * B_N + lane] = s;
  }
}

// =============== K1: serial scan, quad steps ===============
// Per quad: 5 packed loads, 4 muls, 4 interleaved 64-lane DPP reductions,
// 3-fma triangular solve, 4-fma z chain, 4 z-row stores, 1 aligned r store.
// Window-of-16 rescale after quad p % 4 == 3 (step 16m+16), exponent of r4.
// r_ws is indexed by (step-1) so quad r stores are 16B-aligned.
__global__ __launch_bounds__(64, 1) void scan_kernel(
    const float* __restrict__ stop_logps,
    const float* __restrict__ start_logps,
    const float* __restrict__ quadQ,
    float* __restrict__ z_ws,     // (1024,64) rows 1..1023
    float* __restrict__ r_ws,     // 1024; r_ws[i-1] = r at step i
    float* __restrict__ wexp)     // 64 (0..62 used)
{
  const int lane = threadIdx.x;
  const float2* stop2 = (const float2*)stop_logps;

  // prefetch tail-single coefficients (steps 1021..1023) now
  float2 sct0 = stop2[1021 * B_N + lane];
  float2 sct1 = stop2[1022 * B_N + lane];
  float2 sct2 = stop2[1023 * B_N + lane];
  float stt0 = start_logps[1021 * B_N + lane];
  float stt1 = start_logps[1022 * B_N + lane];
  float stt2 = start_logps[1023 * B_N + lane];

  float z = __expf(start_logps[lane]);   // y_0, scale P=0

  const f32x4* qs = (const f32x4*)quadQ;

  // 8-quad (32-step) rotating prefetch
  f32x4 qb[8][5];
  #pragma unroll
  for (int q = 0; q < 8; ++q)
    #pragma unroll
    for (int s = 0; s < 5; ++s)
      qb[q][s] = qs[((size_t)q * 5 + s) * 64 + lane];

  for (int p0 = 0; p0 < 248; p0 += 8) {
    #pragma unroll
    for (int q = 0; q < 8; ++q) {
      const int p  = p0 + q;
      const int i1 = 4 * p + 1;
      f32x4 V   = qb[q][0];
      f32x4 C12 = qb[q][1];
      f32x4 C34 = qb[q][2];
      f32x4 K1  = qb[q][3];
      f32x4 K2  = qb[q][4];
      // prefetch quad p+8 (quad 255 is a dummy slot, loaded but never used)
      {
        const int pn = p + 8;
        #pragma unroll
        for (int s = 0; s < 5; ++s)
          qb[q][s] = qs[((size_t)pn * 5 + s) * 64 + lane];
      }

      float d1, d2, d3, d4;
      wave_sum64_x4(z * V.x, z * V.y, z * V.z, z * V.w, d1, d2, d3, d4);
      float r1 = d1;
      float r2 = __builtin_fmaf(K1.x, r1, d2);
      float r3 = __builtin_fmaf(K1.z, r2, __builtin_fmaf(K1.y, r1, d3));
      float r4 = __builtin_fmaf(K2.y, r3,
                 __builtin_fmaf(K2.x, r2, __builtin_fmaf(K1.w, r1, d4)));

      float z1 = __builtin_fmaf(r1, C12.y, z  * C12.x);
      float z2 = __builtin_fmaf(r2, C12.w, z1 * C12.z);
      float z3 = __builtin_fmaf(r3, C34.y, z2 * C34.x);
      float z4 = __builtin_fmaf(r4, C34.w, z3 * C34.z);
      z_ws[(i1 + 0) * B_N + lane] = z1;
      z_ws[(i1 + 1) * B_N + lane] = z2;
      z_ws[(i1 + 2) * B_N + lane] = z3;
      z_ws[(i1 + 3) * B_N + lane] = z4;
      if (lane == 0) *(f32x4*)(r_ws + 4 * p) = (f32x4){r1, r2, r3, r4};
      z = z4;

      if ((q & 3) == 3) {                 // step 16m+16: window boundary
        int rb  = bci(r4);
        int e16 = ((rb >> 23) & 255) - 127;
        z = ldexpf(z, -e16);
        if (lane == 0) wexp[p >> 2] = (float)e16;
      }
    }
  }
  // tail quads 248..254 (steps 993..1020); rescale only at p==251 (step 1008)
  #pragma unroll
  for (int q = 0; q < 7; ++q) {
    const int p  = 248 + q;
    const int i1 = 4 * p + 1;
    f32x4 V   = qb[q][0];
    f32x4 C12 = qb[q][1];
    f32x4 C34 = qb[q][2];
    f32x4 K1  = qb[q][3];
    f32x4 K2  = qb[q][4];
    float d1, d2, d3, d4;
    wave_sum64_x4(z * V.x, z * V.y, z * V.z, z * V.w, d1, d2, d3, d4);
    float r1 = d1;
    float r2 = __builtin_fmaf(K1.x, r1, d2);
    float r3 = __builtin_fmaf(K1.z, r2, __builtin_fmaf(K1.y, r1, d3));
    float r4 = __builtin_fmaf(K2.y, r3,
               __builtin_fmaf(K2.x, r2, __builtin_fmaf(K1.w, r1, d4)));
    float z1 = __builtin_fmaf(r1, C12.y, z  * C12.x);
    float z2 = __builtin_fmaf(r2, C12.w, z1 * C12.z);
    float z3 = __builtin_fmaf(r3, C34.y, z2 * C34.x);
    float z4 = __builtin_fmaf(r4, C34.w, z3 * C34.z);
    z_ws[(i1 + 0) * B_N + lane] = z1;
    z_ws[(i1 + 1) * B_N + lane] = z2;
    z_ws[(i1 + 2) * B_N + lane] = z3;
    z_ws[(i1 + 3) * B_N + lane] = z4;
    if (lane == 0) *(f32x4*)(r_ws + 4 * p) = (f32x4){r1, r2, r3, r4};
    z = z4;
    if (q == 3) {                         // p==251, step 1008 boundary
      int rb  = bci(r4);
      int e16 = ((rb >> 23) & 255) - 127;
      z = ldexpf(z, -e16);
      if (lane == 0) wexp[62] = (float)e16;
    }
  }
  // singles: steps 1021..1023 (window 63, no rescale)
  const float KAPPA = 0.60653065971263342f;
  {
    float esw = __expf(sct0.x), ecw = __expf(sct0.y), sv = KAPPA * __expf(stt0);
    float r = wave_sum64(z * esw);
    z = __builtin_fmaf(sv, r, z * ecw);
    z_ws[1021 * B_N + lane] = z;
    if (lane == 0) r_ws[1020] = r;
  }
  {
    float esw = __expf(sct1.x), ecw = __expf(sct1.y), sv = KAPPA * __expf(stt1);
    float r = wave_sum64(z * esw);
    z = __builtin_fmaf(sv, r, z * ecw);
    z_ws[1022 * B_N + lane] = z;
    if (lane == 0) r_ws[1021] = r;
  }
  {
    float esw = __expf(sct2.x), ecw = __expf(sct2.y), sv = KAPPA * __expf(stt2);
    float r = wave_sum64(z * esw);
    z = __builtin_fmaf(sv, r, z * ecw);
    z_ws[1023 * B_N + lane] = z;
    if (lane == 0) r_ws[1022] = r;
  }
}

// =============== K2: bookkeeping ===============
__global__ __launch_bounds__(1024) void post_kernel(
    const int* __restrict__ actions,
    const float* __restrict__ action_logps,
    const float* __restrict__ stop_logps,
    const float* __restrict__ start_logps,
    const float* __restrict__ z_ws,
    const float* __restrict__ r_ws,
    const float* __restrict__ wexp,
    const float* __restrict__ cs,
    float* __restrict__ u_ws,
    float* __restrict__ D_ws,
    float* __restrict__ out)
{
  const int tid  = (int)threadIdx.x;
  const int w    = tid >> 6;     // 0..15
  const int lane = tid & 63;     // = b
  const float LN2 = 0.69314718055994531f;
  const float2* stop2 = (const float2*)stop_logps;

  __shared__ float Pw[64];
  if (w == 0) {   // window-scale prefix: Pw[m] = ln2 * sum_{m'<m} wexp[m']
    float psum = 0.f;
    for (int m = 0; m < lane && m < 63; ++m) psum += wexp[m];
    Pw[lane] = psum * LN2;
  }
  __syncthreads();

  float C = 0.f;
  for (int ww = 0; ww < w; ++ww) C += cs[ww * B_N + lane];
  for (int k = 1; k <= 64; ++k) {
    int i = 64 * w + k;
    if (i > 1023) break;
    C += stop2[i * B_N + lane].y;
    float Pv = Pw[(i - 1) >> 4];
    float R  = __logf(r_ws[i - 1]) + Pv - 0.5f;
    u_ws[i * B_N + lane] = start_logps[i * B_N + lane] + R - C;
    float zs = wave_sum64(z_ws[i * B_N + lane]);
    D_ws[i * B_N + lane] = C - (__logf(zs) + Pv);
  }
  if (tid < 64) u_ws[lane] = start_logps[lane];   // u_0 = st0

  if (w == 15) {
    float st0 = start_logps[lane];
    int   a0  = actions[0];
    float al0 = action_logps[lane * A_N + a0];
    float lp0 = __logf(wave_sum64(__expf(st0 + al0)));
    float stopT = stop_logps[(T_N * B_N + lane) * 2 + 0];
    float z1023 = z_ws[1023 * B_N + lane];
    float fin = __logf(wave_sum64(z1023 * __expf(stopT))) + Pw[63];
    if (lane == 0) out[0] = -(lp0 + fin);
  }
}

// =============== K34: fused consistency + logp ===============
// blocks 0..511   : cons rows j = bid and 1023-bid (constant 1025 rows/block)
// blocks 512..1534: logp term for i = 1535-bid (1023..1, longest first)
__global__ __launch_bounds__(256) void cons_logp_kernel(
    const float* __restrict__ cons_pen,
    const float* __restrict__ u_ws,
    const float* __restrict__ D_ws,
    const int* __restrict__ actions,
    const float* __restrict__ action_logps,
    float* __restrict__ A1p,
    float* __restrict__ LQ)
{
  const int bid  = (int)blockIdx.x;
  const int tid  = (int)threadIdx.x;
  const int lane = tid & 63;
  const int wv   = tid >> 6;

  __shared__ float sm[4][64];
  __shared__ float sa[4][64];

  if (bid < 512) {
    const int bq  = (lane & 15) * 4;
    const int row = lane >> 4;
    #pragma unroll
    for (int t = 0; t < 2; ++t) {
      const int j = t ? (1023 - bid) : bid;
      const float4 u4 = *(const float4*)(u_ws + j * B_N + bq);
      float* dst = A1p + ((j & 63) << 10);
      for (int i0 = j + 4 * wv; i0 <= 1023; i0 += 16) {
        int i  = i0 + row;
        int iL = i > 1023 ? 1023 : i;
        f32x4 cp4 = __builtin_nontemporal_load(
            (const f32x4*)(cons_pen + ((size_t)j * TP1 + iL) * B_N + bq));
        float4 d4  = *(const float4*)(D_ws + (size_t)iL * B_N + bq);
        bool valid = (i >= 1) && (i <= 1023);
        float a0 = u4.x + d4.x + cp4.x;
        float a1 = u4.y + d4.y + cp4.y;
        float a2 = u4.z + d4.z + cp4.z;
        float a3 = u4.w + d4.w + cp4.w;
        a0 = valid ? a0 : -1e30f;
        a1 = valid ? a1 : -1e30f;
        a2 = valid ? a2 : -1e30f;
        a3 = valid ? a3 : -1e30f;
        float sred = (__expf(a0) + __expf(a1)) + (__expf(a2) + __expf(a3));
        sred = group16_sum(sred);
        if (((lane & 15) == 15) && valid) atomicAdd(dst + i, sred);
      }
    }
  } else {
    const int i = 1535 - bid;   // 1023..1
    int   ai = actions[i];
    float av = action_logps[((size_t)i * B_N + lane) * A_N + ai];

    // two independent online-softmax chains (halved dependent latency).
    // Padding u1=-1e30 can only pollute chain B while mB==-1e30; the merge
    // weight exp(mB-m) with m>=mA>-1e30 then kills it exactly (exp->0).
    float mA = -1e30f, aA = 0.f, mB = -1e30f, aB = 0.f;
    for (int jj = wv; jj <= i; jj += 8) {
      float u0 = u_ws[jj * B_N + lane];
      int   j1 = jj + 4;
      float u1 = (j1 <= i) ? u_ws[j1 * B_N + lane] : -1e30f;
      float n0 = fmaxf(mA, u0);
      aA = aA * __expf(mA - n0) + __expf(u0 - n0);
      mA = n0;
      float n1 = fmaxf(mB, u1);
      aB = aB * __expf(mB - n1) + __expf(u1 - n1);
      mB = n1;
    }
    float m   = fmaxf(mA, mB);
    float acc = aA * __expf(mA - m) + aB * __expf(mB - m);

    sm[wv][lane] = m; sa[wv][lane] = acc;
    __syncthreads();
    if (wv == 0) {
      float m0 = sm[0][lane], m1 = sm[1][lane], m2 = sm[2][lane], m3 = sm[3][lane];
      float M2 = fmaxf(fmaxf(m0, m1), fmaxf(m2, m3));
      float A  = sa[0][lane] * __expf(m0 - M2) + sa[1][lane] * __expf(m1 - M2)
               + sa[2][lane] * __expf(m2 - M2) + sa[3][lane] * __expf(m3 - M2);
      float S  = M2 + __logf(A);
      float val = S + D_ws[(size_t)i * B_N + lane] + av;
      float mx  = wave_max64(val);
      float sum = wave_sum64(__expf(val - mx));
      if (lane == 0) LQ[i] = mx + __logf(sum);
    }
  }
}

// =============== K5: combine ===============
__global__ __launch_bounds__(256) void finish_kernel(
    const float* __restrict__ A1p,
    const float* __restrict__ LQ,
    float* __restrict__ out)
{
  const int i = (int)blockIdx.x * 256 + (int)threadIdx.x;   // grid 4
  float v = 0.f;
  if (i >= 1 && i <= 1023) {
    float a = 0.f;
    #pragma unroll 8
    for (int p = 0; p < 64; ++p) a += A1p[(p << 10) + i];
    v = __logf(a) - LQ[i];
  }
  float ws = wave_sum64(v);
  __shared__ float sb[4];
  if ((threadIdx.x & 63) == 0) sb[threadIdx.x >> 6] = ws;
  __syncthreads();
  if (threadIdx.x == 0) atomicAdd(out, sb[0] + sb[1] + sb[2] + sb[3]);
}

extern "C" void kernel_launch(void* const* d_in, const int* in_sizes, int n_in,
                              void* d_out, int out_size, void* d_ws, size_t ws_size,
                              hipStream_t stream) {
  const int*   actions      = (const int*)d_in[0];
  const float* action_logps = (const float*)d_in[1];
  const float* stop_logps   = (const float*)d_in[2];
  const float* start_logps  = (const float*)d_in[3];
  const float* cons_pen     = (const float*)d_in[4];
  float* out = (float*)d_out;

  float* z_ws  = (float*)d_ws;                  // 1024*64
  float* u_ws  = z_ws + T_N * B_N;              // 1024*64
  float* D_ws  = u_ws + T_N * B_N;              // 1024*64
  float* A1p   = D_ws + T_N * B_N;              // 64*1024
  float* r_ws  = A1p + 64 * 1024;               // 1024 (16B aligned)
  float* wexp  = r_ws + T_N;                    // 64
  float* LQ    = wexp + 64;                     // 1024
  float* cs    = LQ + T_N;                      // 16*64
  float* quadQ = cs + 16 * B_N;                 // 256*5*64*4 (16B aligned)

  hipLaunchKernelGGL(prep_kernel, dim3(64), dim3(256), 0, stream,
                     stop_logps, start_logps, quadQ, cs, A1p);
  hipLaunchKernelGGL(scan_kernel, dim3(1), dim3(64), 0, stream,
                     stop_logps, start_logps, quadQ, z_ws, r_ws, wexp);
  hipLaunchKernelGGL(post_kernel, dim3(1), dim3(1024), 0, stream,
                     actions, action_logps, stop_logps, start_logps,
                     z_ws, r_ws, wexp, cs, u_ws, D_ws, out);
  hipLaunchKernelGGL(cons_logp_kernel, dim3(1535), dim3(256), 0, stream,
                     cons_pen, u_ws, D_ws, actions, action_logps, A1p, LQ);
  hipLaunchKernelGGL(finish_kernel, dim3(4), dim3(256), 0, stream,
                     A1p, LQ, out);
}

// Round 3
// 481.087 us; speedup vs baseline: 1.1738x; 1.0180x over previous
//
#include <hip/hip_runtime.h>

#define T_N 1024
#define B_N 64
#define A_N 128
#define TP1 1025
// STOP_IX=0, CONT_IX=1, ABSTRACT_PENALTY=0.5, CONSISTENCY_RATIO=1.0

typedef float f32x4 __attribute__((ext_vector_type(4)));

__device__ __forceinline__ float bcf(int x){ return __builtin_bit_cast(float, x); }
__device__ __forceinline__ int   bci(float x){ return __builtin_bit_cast(int, x); }

// ---- DPP helpers ----
template<int CTRL, int RM>
__device__ __forceinline__ float dpp_add_step(float x){
  int t = __builtin_amdgcn_update_dpp(0, bci(x), CTRL, RM, 0xf, true);
  return x + bcf(t);
}
__device__ __forceinline__ float wave_sum64(float x){
  x = dpp_add_step<0x111,0xf>(x);   // row_shr:1
  x = dpp_add_step<0x112,0xf>(x);   // row_shr:2
  x = dpp_add_step<0x114,0xf>(x);   // row_shr:4
  x = dpp_add_step<0x118,0xf>(x);   // row_shr:8
  x = dpp_add_step<0x142,0xa>(x);   // row_bcast15
  x = dpp_add_step<0x143,0xc>(x);   // row_bcast31; lane63 = total
  return bcf(__builtin_amdgcn_readlane(bci(x), 63));
}
// four interleaved reductions: ~1 chain latency for 4 sums
__device__ __forceinline__ void wave_sum64_x4(float a, float b, float c, float d,
                                              float& ra, float& rb, float& rc, float& rd){
  a = dpp_add_step<0x111,0xf>(a); b = dpp_add_step<0x111,0xf>(b);
  c = dpp_add_step<0x111,0xf>(c); d = dpp_add_step<0x111,0xf>(d);
  a = dpp_add_step<0x112,0xf>(a); b = dpp_add_step<0x112,0xf>(b);
  c = dpp_add_step<0x112,0xf>(c); d = dpp_add_step<0x112,0xf>(d);
  a = dpp_add_step<0x114,0xf>(a); b = dpp_add_step<0x114,0xf>(b);
  c = dpp_add_step<0x114,0xf>(c); d = dpp_add_step<0x114,0xf>(d);
  a = dpp_add_step<0x118,0xf>(a); b = dpp_add_step<0x118,0xf>(b);
  c = dpp_add_step<0x118,0xf>(c); d = dpp_add_step<0x118,0xf>(d);
  a = dpp_add_step<0x142,0xa>(a); b = dpp_add_step<0x142,0xa>(b);
  c = dpp_add_step<0x142,0xa>(c); d = dpp_add_step<0x142,0xa>(d);
  a = dpp_add_step<0x143,0xc>(a); b = dpp_add_step<0x143,0xc>(b);
  c = dpp_add_step<0x143,0xc>(c); d = dpp_add_step<0x143,0xc>(d);
  ra = bcf(__builtin_amdgcn_readlane(bci(a), 63));
  rb = bcf(__builtin_amdgcn_readlane(bci(b), 63));
  rc = bcf(__builtin_amdgcn_readlane(bci(c), 63));
  rd = bcf(__builtin_amdgcn_readlane(bci(d), 63));
}
__device__ __forceinline__ float group16_sum(float x){
  x = dpp_add_step<0x111,0xf>(x);
  x = dpp_add_step<0x112,0xf>(x);
  x = dpp_add_step<0x114,0xf>(x);
  x = dpp_add_step<0x118,0xf>(x);
  return x;                          // lane 15 of each 16-group has group sum
}
template<int CTRL, int RM>
__device__ __forceinline__ float dpp_max_step(float x){
  int t = __builtin_amdgcn_update_dpp(bci(-3.4e38f), bci(x), CTRL, RM, 0xf, false);
  return fmaxf(x, bcf(t));
}
__device__ __forceinline__ float wave_max64(float x){
  x = dpp_max_step<0x111,0xf>(x);
  x = dpp_max_step<0x112,0xf>(x);
  x = dpp_max_step<0x114,0xf>(x);
  x = dpp_max_step<0x118,0xf>(x);
  x = dpp_max_step<0x142,0xa>(x);
  x = dpp_max_step<0x143,0xc>(x);
  return bcf(__builtin_amdgcn_readlane(bci(x), 63));
}

// =============== K0: fully-parallel prep (quad coefficients, 4 slots) ===============
// Quad p covers steps i = 4p+1 .. 4p+4 (p = 0..254; steps 1021..1023 are
// singles in the scan). Per quad, 4 packed float4 slots per lane:
//   s0 = {V1,V2,V3,V4}       dot vectors: V1=e1, V2=e2c1, V3=e3c2c1, V4=e4c3c2c1
//   s1 = {Cq,S1,S2,S3}       z4-jump: Cq=c4c3c2c1, S1=c4c3c2*s1, S2=c4c3*s2, S3=c4*s3
//   s2 = {S4,k21,k31,k32}    S4=s4; k's lane-uniform couplings
//   s3 = {k41,k42,k43,0}
// where r1=d1; r2=d2+k21 r1; r3=d3+k31 r1+k32 r2; r4=d4+k41 r1+k42 r2+k43 r3;
//       z4 = Cq z0 + r1 S1 + r2 S2 + r3 S3 + r4 S4.
// Also zeros A1p and computes cont chunk sums cs[16][64].
__global__ __launch_bounds__(256) void prep_kernel(
    const float* __restrict__ stop_logps,
    const float* __restrict__ start_logps,
    float* __restrict__ quadQ,   // [256][4][64][4] (quad 255 = dummy)
    float* __restrict__ cs,      // [16][64]
    float* __restrict__ A1p)     // 64*1024, zeroed here
{
  const int tid  = (int)threadIdx.x;
  const int lane = tid & 63;
  const int wv   = tid >> 6;
  const int p    = (int)blockIdx.x * 4 + wv;   // 0..255
  const float KAPPA = 0.60653065971263342f;    // e^-0.5
  const float2* stop2 = (const float2*)stop_logps;

  // zero A1p: 65536 floats / 16384 threads = 4 each
  int g = (int)blockIdx.x * 256 + tid;
  A1p[g] = 0.f; A1p[g + 16384] = 0.f; A1p[g + 32768] = 0.f; A1p[g + 49152] = 0.f;

  if (p < 255) {
    const int i1 = 4 * p + 1;
    float2 q1 = stop2[(i1 + 0) * B_N + lane];
    float2 q2 = stop2[(i1 + 1) * B_N + lane];
    float2 q3 = stop2[(i1 + 2) * B_N + lane];
    float2 q4 = stop2[(i1 + 3) * B_N + lane];
    float t1 = start_logps[(i1 + 0) * B_N + lane];
    float t2 = start_logps[(i1 + 1) * B_N + lane];
    float t3 = start_logps[(i1 + 2) * B_N + lane];
    float t4 = start_logps[(i1 + 3) * B_N + lane];
    float e1 = __expf(q1.x), c1 = __expf(q1.y), s1 = KAPPA * __expf(t1);
    float e2 = __expf(q2.x), c2 = __expf(q2.y), s2 = KAPPA * __expf(t2);
    float e3 = __expf(q3.x), c3 = __expf(q3.y), s3 = KAPPA * __expf(t3);
    float e4 = __expf(q4.x), c4 = __expf(q4.y), s4 = KAPPA * __expf(t4);

    float c21  = c2 * c1;
    float c321 = c3 * c21;
    float V1 = e1;
    float V2 = e2 * c1;
    float V3 = e3 * c21;
    float V4 = e4 * c321;

    float Cq = c4 * c321;
    float S1 = c4 * c3 * c2 * s1;
    float S2 = c4 * c3 * s2;
    float S3 = c4 * s3;
    float S4 = s4;

    float k21 = wave_sum64(e2 * s1);
    float k31 = wave_sum64(e3 * c2 * s1);
    float k32 = wave_sum64(e3 * s2);
    float k41 = wave_sum64(e4 * c3 * c2 * s1);
    float k42 = wave_sum64(e4 * c3 * s2);
    float k43 = wave_sum64(e4 * s3);

    f32x4* qs = (f32x4*)quadQ;
    size_t base = (size_t)p * 4 * 64 + lane;
    qs[base + 0 * 64] = (f32x4){V1, V2, V3, V4};
    qs[base + 1 * 64] = (f32x4){Cq, S1, S2, S3};
    qs[base + 2 * 64] = (f32x4){S4, k21, k31, k32};
    qs[base + 3 * 64] = (f32x4){k41, k42, k43, 0.f};
  }

  // cont chunk sums (chunk c = i in [64c+1, 64c+64])
  if (blockIdx.x < 16 && wv == 0) {
    int c = (int)blockIdx.x;
    float s = 0.f;
    for (int k = 1; k <= 64; ++k) {
      int i = 64 * c + k;
      if (i <= 1023) s += stop2[i * B_N + lane].y;
    }
    cs[c * B_N + lane] = s;
  }
}

// =============== K1: serial scan, quad steps, z4-jump ===============
// Per quad: 4 packed loads, 4 muls, 4 interleaved 64-lane DPP reductions,
// 6-fma triangular solve, 4-fma+mul z4 jump, aligned r store.
// z rows stored ONLY at chunk boundaries 64,128,...,960 (post reconstructs
// the rest from r_ws + inputs). Stored rows are pre-rescale (window scale).
// Window-of-16 rescale after quads p%4==3 (step 16m+16), exponent of r4.
// r_ws[i-1] = r at step i (16B-aligned quad stores).
__global__ __launch_bounds__(64, 1) void scan_kernel(
    const float* __restrict__ stop_logps,
    const float* __restrict__ start_logps,
    const float* __restrict__ quadQ,
    float* __restrict__ z_ws,     // rows 64w (w=1..15) only
    float* __restrict__ r_ws,     // 1024; r_ws[i-1] = r at step i
    float* __restrict__ wexp)     // 64 (0..62 used)
{
  const int lane = threadIdx.x;
  const float2* stop2 = (const float2*)stop_logps;

  // prefetch tail-single coefficients (steps 1021..1023) now
  float2 sct0 = stop2[1021 * B_N + lane];
  float2 sct1 = stop2[1022 * B_N + lane];
  float2 sct2 = stop2[1023 * B_N + lane];
  float stt0 = start_logps[1021 * B_N + lane];
  float stt1 = start_logps[1022 * B_N + lane];
  float stt2 = start_logps[1023 * B_N + lane];

  float z = __expf(start_logps[lane]);   // y_0, scale P=0

  const f32x4* qs = (const f32x4*)quadQ;

  // 8-quad (32-step) rotating prefetch
  f32x4 qb[8][4];
  #pragma unroll
  for (int q = 0; q < 8; ++q)
    #pragma unroll
    for (int s = 0; s < 4; ++s)
      qb[q][s] = qs[((size_t)q * 4 + s) * 64 + lane];

  for (int p0 = 0; p0 < 248; p0 += 8) {
    #pragma unroll
    for (int q = 0; q < 8; ++q) {
      const int p = p0 + q;
      f32x4 V = qb[q][0];
      f32x4 Z = qb[q][1];
      f32x4 W = qb[q][2];
      f32x4 X = qb[q][3];
      // prefetch quad p+8 (quad 255 is a dummy slot, loaded but never used)
      {
        const int pn = p + 8;
        #pragma unroll
        for (int s = 0; s < 4; ++s)
          qb[q][s] = qs[((size_t)pn * 4 + s) * 64 + lane];
      }

      float d1, d2, d3, d4;
      wave_sum64_x4(z * V.x, z * V.y, z * V.z, z * V.w, d1, d2, d3, d4);
      float r1 = d1;
      float r2 = __builtin_fmaf(W.y, r1, d2);
      float r3 = __builtin_fmaf(W.w, r2, __builtin_fmaf(W.z, r1, d3));
      float r4 = __builtin_fmaf(X.z, r3,
                 __builtin_fmaf(X.y, r2, __builtin_fmaf(X.x, r1, d4)));
      if (lane == 0) *(f32x4*)(r_ws + 4 * p) = (f32x4){r1, r2, r3, r4};

      z = __builtin_fmaf(r4, W.x,
          __builtin_fmaf(r3, Z.w,
          __builtin_fmaf(r2, Z.z,
          __builtin_fmaf(r1, Z.y, z * Z.x))));

      if (q == 7 && (p0 & 8)) {           // p%16==15: row 4p+4 = 64-multiple
        z_ws[(4 * p + 4) * B_N + lane] = z;   // pre-rescale (window scale)
      }
      if ((q & 3) == 3) {                 // step 16m+16: window boundary
        int rb  = bci(r4);
        int e16 = ((rb >> 23) & 255) - 127;
        z = ldexpf(z, -e16);
        if (lane == 0) wexp[p >> 2] = (float)e16;
      }
    }
  }
  // tail quads 248..254 (steps 993..1020); rescale only at p==251 (step 1008)
  #pragma unroll
  for (int q = 0; q < 7; ++q) {
    f32x4 V = qb[q][0];
    f32x4 Z = qb[q][1];
    f32x4 W = qb[q][2];
    f32x4 X = qb[q][3];
    float d1, d2, d3, d4;
    wave_sum64_x4(z * V.x, z * V.y, z * V.z, z * V.w, d1, d2, d3, d4);
    float r1 = d1;
    float r2 = __builtin_fmaf(W.y, r1, d2);
    float r3 = __builtin_fmaf(W.w, r2, __builtin_fmaf(W.z, r1, d3));
    float r4 = __builtin_fmaf(X.z, r3,
               __builtin_fmaf(X.y, r2, __builtin_fmaf(X.x, r1, d4)));
    if (lane == 0) *(f32x4*)(r_ws + 4 * (248 + q)) = (f32x4){r1, r2, r3, r4};
    z = __builtin_fmaf(r4, W.x,
        __builtin_fmaf(r3, Z.w,
        __builtin_fmaf(r2, Z.z,
        __builtin_fmaf(r1, Z.y, z * Z.x))));
    if (q == 3) {                         // p==251, step 1008 boundary
      int rb  = bci(r4);
      int e16 = ((rb >> 23) & 255) - 127;
      z = ldexpf(z, -e16);
      if (lane == 0) wexp[62] = (float)e16;
    }
  }
  // singles: steps 1021..1023 (window 63, no rescale; r only)
  const float KAPPA = 0.60653065971263342f;
  {
    float esw = __expf(sct0.x), ecw = __expf(sct0.y), sv = KAPPA * __expf(stt0);
    float r = wave_sum64(z * esw);
    z = __builtin_fmaf(sv, r, z * ecw);
    if (lane == 0) r_ws[1020] = r;
  }
  {
    float esw = __expf(sct1.x), ecw = __expf(sct1.y), sv = KAPPA * __expf(stt1);
    float r = wave_sum64(z * esw);
    z = __builtin_fmaf(sv, r, z * ecw);
    if (lane == 0) r_ws[1021] = r;
  }
  {
    float esw = __expf(sct2.x), ecw = __expf(sct2.y), sv = KAPPA * __expf(stt2);
    float r = wave_sum64(z * esw);
    z = __builtin_fmaf(sv, r, z * ecw);
    if (lane == 0) r_ws[1022] = r;
  }
}

// =============== K2: bookkeeping, 16 parallel blocks (1 wave each) ===============
// Block w handles i in [64w+1, min(64w+64,1023)]. Reconstructs z via
// z_i = c_i z_{i-1} + r_i s_i from r_ws + inputs; chunk-entry z from the
// scan's stored boundary row (ldexp'd into the current window scale).
__global__ __launch_bounds__(64) void post_kernel(
    const int* __restrict__ actions,
    const float* __restrict__ action_logps,
    const float* __restrict__ stop_logps,
    const float* __restrict__ start_logps,
    const float* __restrict__ z_ws,
    const float* __restrict__ r_ws,
    const float* __restrict__ wexp,
    const float* __restrict__ cs,
    float* __restrict__ u_ws,
    float* __restrict__ D_ws,
    float* __restrict__ out)
{
  const int w    = (int)blockIdx.x;   // 0..15
  const int lane = (int)threadIdx.x;  // = b
  const float LN2   = 0.69314718055994531f;
  const float KAPPA = 0.60653065971263342f;
  const float2* stop2 = (const float2*)stop_logps;

  float wl = (lane < 63) ? wexp[lane] : 0.f;

  // window-scale prefix entering window 4w
  float Pv = LN2 * wave_sum64((lane < 4 * w) ? wl : 0.f);
  // boundary exponents for windows 4w, 4w+1, 4w+2 (applied after k=16,32,48)
  float e0 = bcf(__builtin_amdgcn_readlane(bci(wl), 4 * w + 0));
  float e1 = bcf(__builtin_amdgcn_readlane(bci(wl), 4 * w + 1));
  float e2 = bcf(__builtin_amdgcn_readlane(bci(wl), 4 * w + 2));

  // cont-logp prefix entering the chunk
  float C = 0.f;
  for (int ww = 0; ww < w; ++ww) C += cs[ww * B_N + lane];

  // chunk-entry z (window-4w scale)
  float z;
  if (w == 0) {
    z = __expf(start_logps[lane]);
    u_ws[lane] = start_logps[lane];       // u_0 = st0
  } else {
    float em = bcf(__builtin_amdgcn_readlane(bci(wl), 4 * w - 1));
    z = ldexpf(z_ws[(64 * w) * B_N + lane], -(int)em);
  }

  for (int k = 1; k <= 64; ++k) {
    int i = 64 * w + k;
    if (i > 1023) break;
    float cont = stop2[i * B_N + lane].y;
    float stv  = start_logps[i * B_N + lane];
    float r    = r_ws[i - 1];
    C += cont;
    float ecw = __expf(cont);
    float sv  = KAPPA * __expf(stv);
    z = __builtin_fmaf(r, sv, ecw * z);
    float zs = wave_sum64(z);
    float R  = __logf(r) + Pv - 0.5f;
    u_ws[i * B_N + lane] = stv + R - C;
    D_ws[i * B_N + lane] = C - (__logf(zs) + Pv);
    if (k == 16)      { z = ldexpf(z, -(int)e0); Pv += LN2 * e0; }
    else if (k == 32) { z = ldexpf(z, -(int)e1); Pv += LN2 * e1; }
    else if (k == 48) { z = ldexpf(z, -(int)e2); Pv += LN2 * e2; }
  }

  if (w == 15) {                          // z = z_1023 (window-63 scale), Pv = Pw[63]
    float st0 = start_logps[lane];
    int   a0  = actions[0];
    float al0 = action_logps[lane * A_N + a0];
    float lp0 = __logf(wave_sum64(__expf(st0 + al0)));
    float stopT = stop_logps[(T_N * B_N + lane) * 2 + 0];
    float fin = __logf(wave_sum64(z * __expf(stopT))) + Pv;
    if (lane == 0) out[0] = -(lp0 + fin);
  }
}

// =============== K34: fused consistency + logp ===============
// blocks 0..511   : cons rows j = bid and 1023-bid (constant 1025 rows/block)
// blocks 512..1534: logp term for i = 1535-bid (1023..1, longest first)
__global__ __launch_bounds__(256) void cons_logp_kernel(
    const float* __restrict__ cons_pen,
    const float* __restrict__ u_ws,
    const float* __restrict__ D_ws,
    const int* __restrict__ actions,
    const float* __restrict__ action_logps,
    float* __restrict__ A1p,
    float* __restrict__ LQ)
{
  const int bid  = (int)blockIdx.x;
  const int tid  = (int)threadIdx.x;
  const int lane = tid & 63;
  const int wv   = tid >> 6;

  __shared__ float sm[4][64];
  __shared__ float sa[4][64];

  if (bid < 512) {
    const int bq  = (lane & 15) * 4;
    const int row = lane >> 4;
    #pragma unroll
    for (int t = 0; t < 2; ++t) {
      const int j = t ? (1023 - bid) : bid;
      const float4 u4 = *(const float4*)(u_ws + j * B_N + bq);
      float* dst = A1p + ((j & 63) << 10);
      for (int i0 = j + 4 * wv; i0 <= 1023; i0 += 16) {
        int i  = i0 + row;
        int iL = i > 1023 ? 1023 : i;
        f32x4 cp4 = __builtin_nontemporal_load(
            (const f32x4*)(cons_pen + ((size_t)j * TP1 + iL) * B_N + bq));
        float4 d4  = *(const float4*)(D_ws + (size_t)iL * B_N + bq);
        bool valid = (i >= 1) && (i <= 1023);
        float a0 = u4.x + d4.x + cp4.x;
        float a1 = u4.y + d4.y + cp4.y;
        float a2 = u4.z + d4.z + cp4.z;
        float a3 = u4.w + d4.w + cp4.w;
        a0 = valid ? a0 : -1e30f;
        a1 = valid ? a1 : -1e30f;
        a2 = valid ? a2 : -1e30f;
        a3 = valid ? a3 : -1e30f;
        float sred = (__expf(a0) + __expf(a1)) + (__expf(a2) + __expf(a3));
        sred = group16_sum(sred);
        if (((lane & 15) == 15) && valid) atomicAdd(dst + i, sred);
      }
    }
  } else {
    const int i = 1535 - bid;   // 1023..1
    int   ai = actions[i];
    float av = action_logps[((size_t)i * B_N + lane) * A_N + ai];

    // two independent online-softmax chains (halved dependent latency)
    float mA = -1e30f, aA = 0.f, mB = -1e30f, aB = 0.f;
    for (int jj = wv; jj <= i; jj += 8) {
      float u0 = u_ws[jj * B_N + lane];
      int   j1 = jj + 4;
      float u1 = (j1 <= i) ? u_ws[j1 * B_N + lane] : -1e30f;
      float n0 = fmaxf(mA, u0);
      aA = aA * __expf(mA - n0) + __expf(u0 - n0);
      mA = n0;
      float n1 = fmaxf(mB, u1);
      aB = aB * __expf(mB - n1) + __expf(u1 - n1);
      mB = n1;
    }
    float m   = fmaxf(mA, mB);
    float acc = aA * __expf(mA - m) + aB * __expf(mB - m);

    sm[wv][lane] = m; sa[wv][lane] = acc;
    __syncthreads();
    if (wv == 0) {
      float m0 = sm[0][lane], m1 = sm[1][lane], m2 = sm[2][lane], m3 = sm[3][lane];
      float M2 = fmaxf(fmaxf(m0, m1), fmaxf(m2, m3));
      float A  = sa[0][lane] * __expf(m0 - M2) + sa[1][lane] * __expf(m1 - M2)
               + sa[2][lane] * __expf(m2 - M2) + sa[3][lane] * __expf(m3 - M2);
      float S  = M2 + __logf(A);
      float val = S + D_ws[(size_t)i * B_N + lane] + av;
      float mx  = wave_max64(val);
      float sum = wave_sum64(__expf(val - mx));
      if (lane == 0) LQ[i] = mx + __logf(sum);
    }
  }
}

// =============== K5: combine ===============
__global__ __launch_bounds__(256) void finish_kernel(
    const float* __restrict__ A1p,
    const float* __restrict__ LQ,
    float* __restrict__ out)
{
  const int i = (int)blockIdx.x * 256 + (int)threadIdx.x;   // grid 4
  float v = 0.f;
  if (i >= 1 && i <= 1023) {
    float a = 0.f;
    #pragma unroll 8
    for (int p = 0; p < 64; ++p) a += A1p[(p << 10) + i];
    v = __logf(a) - LQ[i];
  }
  float ws = wave_sum64(v);
  __shared__ float sb[4];
  if ((threadIdx.x & 63) == 0) sb[threadIdx.x >> 6] = ws;
  __syncthreads();
  if (threadIdx.x == 0) atomicAdd(out, sb[0] + sb[1] + sb[2] + sb[3]);
}

extern "C" void kernel_launch(void* const* d_in, const int* in_sizes, int n_in,
                              void* d_out, int out_size, void* d_ws, size_t ws_size,
                              hipStream_t stream) {
  const int*   actions      = (const int*)d_in[0];
  const float* action_logps = (const float*)d_in[1];
  const float* stop_logps   = (const float*)d_in[2];
  const float* start_logps  = (const float*)d_in[3];
  const float* cons_pen     = (const float*)d_in[4];
  float* out = (float*)d_out;

  float* z_ws  = (float*)d_ws;                  // 1024*64 (only rows 64w used)
  float* u_ws  = z_ws + T_N * B_N;              // 1024*64
  float* D_ws  = u_ws + T_N * B_N;              // 1024*64
  float* A1p   = D_ws + T_N * B_N;              // 64*1024
  float* r_ws  = A1p + 64 * 1024;               // 1024 (16B aligned)
  float* wexp  = r_ws + T_N;                    // 64
  float* LQ    = wexp + 64;                     // 1024
  float* cs    = LQ + T_N;                      // 16*64
  float* quadQ = cs + 16 * B_N;                 // 256*4*64*4 (16B aligned)

  hipLaunchKernelGGL(prep_kernel, dim3(64), dim3(256), 0, stream,
                     stop_logps, start_logps, quadQ, cs, A1p);
  hipLaunchKernelGGL(scan_kernel, dim3(1), dim3(64), 0, stream,
                     stop_logps, start_logps, quadQ, z_ws, r_ws, wexp);
  hipLaunchKernelGGL(post_kernel, dim3(16), dim3(64), 0, stream,
                     actions, action_logps, stop_logps, start_logps,
                     z_ws, r_ws, wexp, cs, u_ws, D_ws, out);
  hipLaunchKernelGGL(cons_logp_kernel, dim3(1535), dim3(256), 0, stream,
                     cons_pen, u_ws, D_ws, actions, action_logps, A1p, LQ);
  hipLaunchKernelGGL(finish_kernel, dim3(4), dim3(256), 0, stream,
                     A1p, LQ, out);
}